// Round 2
// baseline (367.916 us; speedup 1.0000x reference)
//
#include <hip/hip_runtime.h>
#include <hip/hip_bf16.h>

// KAN layer as augmented GEMM:
//   Af[b, c*1024+i] = c==0 ? silu(x[b,i]) : basis_{c-1}(x[b,i])   (bf16)
//   Wf[o, c*1024+i] = c==0 ? base_w[o,i]  : spline_w[o,i,c-1]     (bf16)
//   out = Af @ Wf^T  (fp32 accum via MFMA)
// GEMM: 256x128 tile, BK=64, 8 waves (4Mx2N), 3-buffer LDS ring,
// prefetch distance 2, counted vmcnt(6), T2 XOR-swizzle, T5 setprio,
// T1 bijective XCD swizzle. 1 block/CU, grid=256.
#define B_DIM 8192
#define I_DIM 1024
#define O_DIM 1024
#define K_DIM 9216   // 9 * 1024

#define BM 256
#define BN 128
#define BK 64
#define NKT (K_DIM / BK)        // 144
#define A_TILE (BM * BK)        // 16384 elems
#define B_TILE (BN * BK)        // 8192 elems

typedef __attribute__((ext_vector_type(8))) short short8;
typedef __attribute__((ext_vector_type(4))) float f32x4;

#define MFMA(a, b, c) __builtin_amdgcn_mfma_f32_16x16x32_bf16((a), (b), (c), 0, 0, 0)

__device__ __forceinline__ unsigned short f2bf(float f) {
    unsigned u = __float_as_uint(f);
    unsigned r = 0x7fffu + ((u >> 16) & 1u);
    return (unsigned short)((u + r) >> 16);
}

__device__ __forceinline__ void llds16(const unsigned short* g, unsigned short* l) {
    __builtin_amdgcn_global_load_lds(
        (const __attribute__((address_space(1))) unsigned int*)g,
        (__attribute__((address_space(3))) unsigned int*)l,
        16, 0, 0);
}

// ---------------- expansion: weights ----------------
__global__ __launch_bounds__(256) void expand_w_kernel(
        const float* __restrict__ bw, const float* __restrict__ sw,
        unsigned short* __restrict__ Wf) {
    int idx = blockIdx.x * 256 + threadIdx.x;   // one thread: (o, 2 consecutive i)
    int o = idx >> 9;
    int i = (idx & 511) << 1;
    unsigned short* out = Wf + (size_t)o * K_DIM + i;
    const float* bp = bw + ((size_t)o << 10) + i;
    *(unsigned*)out = (unsigned)f2bf(bp[0]) | ((unsigned)f2bf(bp[1]) << 16);
    const float* sp = sw + (((size_t)o << 10) + i) * 8;   // 16 contiguous floats
    float v[16];
    #pragma unroll
    for (int n = 0; n < 16; ++n) v[n] = sp[n];
    #pragma unroll
    for (int n = 0; n < 8; ++n)
        *(unsigned*)(out + (size_t)(n + 1) * 1024) =
            (unsigned)f2bf(v[n]) | ((unsigned)f2bf(v[8 + n]) << 16);
}

// ---------------- expansion: activations ----------------
__global__ __launch_bounds__(256) void expand_a_kernel(
        const float* __restrict__ x, unsigned short* __restrict__ Af) {
    int idx = blockIdx.x * 256 + threadIdx.x;   // one thread: (b, 2 consecutive i)
    int b = idx >> 9;
    int i = (idx & 511) << 1;
    const float* xp = x + ((size_t)b << 10) + i;
    float x0 = xp[0], x1 = xp[1];
    unsigned short* out = Af + (size_t)b * K_DIM + i;
    float s0 = x0 / (1.0f + __expf(-x0));
    float s1 = x1 / (1.0f + __expf(-x1));
    *(unsigned*)out = (unsigned)f2bf(s0) | ((unsigned)f2bf(s1) << 16);
    // quadratic B-spline basis, uniform knots -9..9 step 1.8
    float t0 = (x0 + 9.0f) * (1.0f / 1.8f);
    float t1 = (x1 + 9.0f) * (1.0f / 1.8f);
    float fj0 = floorf(t0), fj1 = floorf(t1);
    int j0 = (int)fj0, j1 = (int)fj1;
    float u0 = t0 - fj0, u1 = t1 - fj1;
    float p0 = 0.5f * (1.f - u0) * (1.f - u0);
    float p1 = 0.5f * (-2.f * u0 * u0 + 2.f * u0 + 1.f);
    float p2 = 0.5f * u0 * u0;
    float q0 = 0.5f * (1.f - u1) * (1.f - u1);
    float q1 = 0.5f * (-2.f * u1 * u1 + 2.f * u1 + 1.f);
    float q2 = 0.5f * u1 * u1;
    #pragma unroll
    for (int n = 0; n < 8; ++n) {
        float v0 = (n == j0 - 2) ? p0 : (n == j0 - 1) ? p1 : (n == j0) ? p2 : 0.f;
        float v1 = (n == j1 - 2) ? q0 : (n == j1 - 1) ? q1 : (n == j1) ? q2 : 0.f;
        *(unsigned*)(out + (size_t)(n + 1) * 1024) =
            (unsigned)f2bf(v0) | ((unsigned)f2bf(v1) << 16);
    }
}

// ---------------- GEMM: out[M=8192, N=1024] = Af[M,K] * Wf[N,K]^T ----------------
__global__ __launch_bounds__(512, 2) void gemm_bt(
        const unsigned short* __restrict__ Af,
        const unsigned short* __restrict__ Wf,
        float* __restrict__ out) {
    // 3-buffer ring: A 96KB + B 48KB = 144KB LDS
    __shared__ __align__(16) unsigned short As[3][A_TILE];
    __shared__ __align__(16) unsigned short Bs[3][B_TILE];

    const int tid = threadIdx.x;

    // T1: bijective XCD swizzle (nwg=256 divisible by 8)
    const int orig = blockIdx.x;
    const int wgid = (orig & 7) * 32 + (orig >> 3);
    const int bm = wgid >> 3;               // 0..31
    const int bn = wgid & 7;                // 0..7
    const int mBase = bm * BM, nBase = bn * BN;

    const int lane = tid & 63;
    const int w = tid >> 6;                 // 8 waves: 4M x 2N
    const int wr = (w >> 1) * 64, wc = (w & 1) * 64;
    const int fr = lane & 15;
    const int kg = lane >> 4;               // k-group 0..3

    // staging (per round: 512 lanes x 16B; A: 4 rounds, B: 2 rounds per tile)
    const int srow = tid >> 3;                                   // 0..63
    const int scolE = ((tid & 7) * 8) ^ ((srow & 7) << 3);       // pre-swizzled source col
    const int sdst = (tid & ~63) * 8;                            // wave-uniform elem offset

    auto stageA = [&](int t, int buf, int r) {
        int row = r * 64 + srow;
        const unsigned short* g = Af + (size_t)(mBase + row) * K_DIM + t * BK + scolE;
        llds16(g, &As[buf][r * 4096 + sdst]);
    };
    auto stageB = [&](int t, int buf, int r) {
        int row = r * 64 + srow;
        const unsigned short* g = Wf + (size_t)(nBase + row) * K_DIM + t * BK + scolE;
        llds16(g, &Bs[buf][r * 4096 + sdst]);
    };

    // fragment read offsets (loop-invariant): row*64 + ((kk*32+kg*8) ^ ((row&7)<<3))
    int offA[4][2], offB[4][2];
    #pragma unroll
    for (int m = 0; m < 4; ++m) {
        int row = wr + m * 16 + fr;
        #pragma unroll
        for (int kk = 0; kk < 2; ++kk)
            offA[m][kk] = row * 64 + ((kk * 32 + kg * 8) ^ ((row & 7) << 3));
    }
    #pragma unroll
    for (int n = 0; n < 4; ++n) {
        int row = wc + n * 16 + fr;
        #pragma unroll
        for (int kk = 0; kk < 2; ++kk)
            offB[n][kk] = row * 64 + ((kk * 32 + kg * 8) ^ ((row & 7) << 3));
    }

    f32x4 acc[4][4];
    #pragma unroll
    for (int m = 0; m < 4; ++m)
        #pragma unroll
        for (int n = 0; n < 4; ++n) acc[m][n] = (f32x4){0.f, 0.f, 0.f, 0.f};

    // prologue: tile0 -> buf0, tile1 -> buf1 (6 loads each per wave)
    stageA(0, 0, 0); stageA(0, 0, 1); stageA(0, 0, 2); stageA(0, 0, 3);
    stageB(0, 0, 0); stageB(0, 0, 1);
    stageA(1, 1, 0); stageA(1, 1, 1); stageA(1, 1, 2); stageA(1, 1, 3);
    stageB(1, 1, 0); stageB(1, 1, 1);

    int c = 0;   // buffer holding tile t
    for (int t = 0; t < NKT; ++t) {
        // tile t's 6 loads complete (newest 6 outstanding = tile t+1's)
        if (t + 1 < NKT) asm volatile("s_waitcnt vmcnt(6)" ::: "memory");
        else             asm volatile("s_waitcnt vmcnt(0)" ::: "memory");
        __builtin_amdgcn_s_barrier();
        __builtin_amdgcn_sched_barrier(0);

        const int pf = (c + 2 >= 3) ? c - 1 : c + 2;
        const bool dopf = (t + 2 < NKT);
        const int tp = t + 2;
        const unsigned short* A_ = As[c];
        const unsigned short* B_ = Bs[c];

#define PHASE(MH, NH, PREFETCH)                                                  \
        {                                                                         \
            PREFETCH;                                                             \
            short8 a00 = *(const short8*)&A_[offA[2*MH+0][0]];                    \
            short8 a01 = *(const short8*)&A_[offA[2*MH+0][1]];                    \
            short8 a10 = *(const short8*)&A_[offA[2*MH+1][0]];                    \
            short8 a11 = *(const short8*)&A_[offA[2*MH+1][1]];                    \
            short8 b00 = *(const short8*)&B_[offB[2*NH+0][0]];                    \
            short8 b01 = *(const short8*)&B_[offB[2*NH+0][1]];                    \
            short8 b10 = *(const short8*)&B_[offB[2*NH+1][0]];                    \
            short8 b11 = *(const short8*)&B_[offB[2*NH+1][1]];                    \
            __builtin_amdgcn_s_barrier();                                         \
            asm volatile("s_waitcnt lgkmcnt(0)" ::: "memory");                    \
            __builtin_amdgcn_sched_barrier(0);                                    \
            __builtin_amdgcn_s_setprio(1);                                        \
            acc[2*MH+0][2*NH+0] = MFMA(a00, b00, acc[2*MH+0][2*NH+0]);            \
            acc[2*MH+0][2*NH+0] = MFMA(a01, b01, acc[2*MH+0][2*NH+0]);            \
            acc[2*MH+0][2*NH+1] = MFMA(a00, b10, acc[2*MH+0][2*NH+1]);            \
            acc[2*MH+0][2*NH+1] = MFMA(a01, b11, acc[2*MH+0][2*NH+1]);            \
            acc[2*MH+1][2*NH+0] = MFMA(a10, b00, acc[2*MH+1][2*NH+0]);            \
            acc[2*MH+1][2*NH+0] = MFMA(a11, b01, acc[2*MH+1][2*NH+0]);            \
            acc[2*MH+1][2*NH+1] = MFMA(a10, b10, acc[2*MH+1][2*NH+1]);            \
            acc[2*MH+1][2*NH+1] = MFMA(a11, b11, acc[2*MH+1][2*NH+1]);            \
            __builtin_amdgcn_s_setprio(0);                                        \
            __builtin_amdgcn_s_barrier();                                         \
        }

        PHASE(0, 0, if (dopf) { stageA(tp, pf, 0); stageA(tp, pf, 1); })
        PHASE(0, 1, if (dopf) { stageA(tp, pf, 2); stageA(tp, pf, 3); })
        PHASE(1, 0, if (dopf) { stageB(tp, pf, 0); })
        PHASE(1, 1, if (dopf) { stageB(tp, pf, 1); })
#undef PHASE

        c = (c + 1 == 3) ? 0 : c + 1;
    }

    // epilogue: C/D layout col=lane&15, row=(lane>>4)*4+r
    const int orow = (lane >> 4) * 4;
    const int ocol = lane & 15;
    #pragma unroll
    for (int m = 0; m < 4; ++m)
        #pragma unroll
        for (int n = 0; n < 4; ++n) {
            size_t base = (size_t)(mBase + wr + m * 16 + orow) * O_DIM
                        + (nBase + wc + n * 16 + ocol);
            #pragma unroll
            for (int r = 0; r < 4; ++r)
                out[base + (size_t)r * O_DIM] = acc[m][n][r];
        }
}

extern "C" void kernel_launch(void* const* d_in, const int* in_sizes, int n_in,
                              void* d_out, int out_size, void* d_ws, size_t ws_size,
                              hipStream_t stream) {
    const float* x  = (const float*)d_in[0];
    const float* bw = (const float*)d_in[1];
    const float* sw = (const float*)d_in[2];
    float* out = (float*)d_out;

    // ws layout: Wf [1024 x 9216] bf16 (18.9 MB) then Af [8192 x 9216] bf16 (151 MB)
    unsigned short* Wf = (unsigned short*)d_ws;
    unsigned short* Af = Wf + (size_t)O_DIM * K_DIM;

    expand_w_kernel<<<(O_DIM * I_DIM / 2) / 256, 256, 0, stream>>>(bw, sw, Wf);
    expand_a_kernel<<<(B_DIM * I_DIM / 2) / 256, 256, 0, stream>>>(x, Af);
    gemm_bt<<<(B_DIM / BM) * (O_DIM / BN), 512, 0, stream>>>(Af, Wf, out);
}

// Round 3
// 234.857 us; speedup vs baseline: 1.5666x; 1.5666x over previous
//
#include <hip/hip_runtime.h>
#include <hip/hip_bf16.h>

// KAN layer as augmented GEMM:
//   Af[b, c*1024+i] = c==0 ? silu(x[b,i]) : basis_{c-1}(x[b,i])   (bf16)
//   Wf[o, c*1024+i] = c==0 ? base_w[o,i]  : spline_w[o,i,c-1]     (bf16)
//   out = Af @ Wf^T  (fp32 accum via MFMA)
//
// GEMM: m97-style 128x128 tile, BK=32, 4 waves (2x2 of 64x64), dbuf LDS
// (32KB -> up to 5 blocks/CU), split-K=2 -> grid 1024 = 4 blocks/CU,
// T1 bijective XCD swizzle, T2 source+read XOR swizzle, width-16
// global_load_lds staging. Split-0 writes d_out, split-1 writes ws
// partial; vectorized reduce sums them.
#define B_DIM 8192
#define I_DIM 1024
#define O_DIM 1024
#define K_DIM 9216   // 9 * 1024

#define BM 128
#define BN 128
#define BK 32

typedef unsigned short ushort_t;
typedef __attribute__((ext_vector_type(8))) short short8;
typedef __attribute__((ext_vector_type(4))) float f32x4;

#define MFMA(a, b, c) __builtin_amdgcn_mfma_f32_16x16x32_bf16((a), (b), (c), 0, 0, 0)

__device__ __forceinline__ ushort_t f2bf(float f) {
    unsigned u = __float_as_uint(f);
    unsigned r = 0x7fffu + ((u >> 16) & 1u);
    return (ushort_t)((u + r) >> 16);
}

__device__ __forceinline__ void llds16(const ushort_t* g, ushort_t* l) {
    __builtin_amdgcn_global_load_lds(
        (const __attribute__((address_space(1))) unsigned int*)g,
        (__attribute__((address_space(3))) unsigned int*)l,
        16, 0, 0);
}

// ---------------- expansion: weights ----------------
__global__ __launch_bounds__(256) void expand_w_kernel(
        const float* __restrict__ bw, const float* __restrict__ sw,
        ushort_t* __restrict__ Wf) {
    int idx = blockIdx.x * 256 + threadIdx.x;   // one thread: (o, 2 consecutive i)
    int o = idx >> 9;
    int i = (idx & 511) << 1;
    ushort_t* out = Wf + (size_t)o * K_DIM + i;
    const float* bp = bw + ((size_t)o << 10) + i;
    *(unsigned*)out = (unsigned)f2bf(bp[0]) | ((unsigned)f2bf(bp[1]) << 16);
    const float* sp = sw + (((size_t)o << 10) + i) * 8;   // 16 contiguous floats
    float v[16];
    #pragma unroll
    for (int n = 0; n < 16; ++n) v[n] = sp[n];
    #pragma unroll
    for (int n = 0; n < 8; ++n)
        *(unsigned*)(out + (size_t)(n + 1) * 1024) =
            (unsigned)f2bf(v[n]) | ((unsigned)f2bf(v[8 + n]) << 16);
}

// ---------------- expansion: activations ----------------
__global__ __launch_bounds__(256) void expand_a_kernel(
        const float* __restrict__ x, ushort_t* __restrict__ Af) {
    int idx = blockIdx.x * 256 + threadIdx.x;   // one thread: (b, 2 consecutive i)
    int b = idx >> 9;
    int i = (idx & 511) << 1;
    const float* xp = x + ((size_t)b << 10) + i;
    float x0 = xp[0], x1 = xp[1];
    ushort_t* out = Af + (size_t)b * K_DIM + i;
    float s0 = x0 / (1.0f + __expf(-x0));
    float s1 = x1 / (1.0f + __expf(-x1));
    *(unsigned*)out = (unsigned)f2bf(s0) | ((unsigned)f2bf(s1) << 16);
    // quadratic B-spline basis, uniform knots -9..9 step 1.8
    float t0 = (x0 + 9.0f) * (1.0f / 1.8f);
    float t1 = (x1 + 9.0f) * (1.0f / 1.8f);
    float fj0 = floorf(t0), fj1 = floorf(t1);
    int j0 = (int)fj0, j1 = (int)fj1;
    float u0 = t0 - fj0, u1 = t1 - fj1;
    float p0 = 0.5f * (1.f - u0) * (1.f - u0);
    float p1 = 0.5f * (-2.f * u0 * u0 + 2.f * u0 + 1.f);
    float p2 = 0.5f * u0 * u0;
    float q0 = 0.5f * (1.f - u1) * (1.f - u1);
    float q1 = 0.5f * (-2.f * u1 * u1 + 2.f * u1 + 1.f);
    float q2 = 0.5f * u1 * u1;
    #pragma unroll
    for (int n = 0; n < 8; ++n) {
        float v0 = (n == j0 - 2) ? p0 : (n == j0 - 1) ? p1 : (n == j0) ? p2 : 0.f;
        float v1 = (n == j1 - 2) ? q0 : (n == j1 - 1) ? q1 : (n == j1) ? q2 : 0.f;
        *(unsigned*)(out + (size_t)(n + 1) * 1024) =
            (unsigned)f2bf(v0) | ((unsigned)f2bf(v1) << 16);
    }
}

// ---------------- GEMM: out[M=8192, N=1024] = Af[M,K] * Wf[N,K]^T ----------------
// grid = 512 * nsplit blocks; wgid = split*512 + bm*8 + bn.
__global__ __launch_bounds__(256) void gemm_bt(
        const ushort_t* __restrict__ Af,
        const ushort_t* __restrict__ Wf,
        float* __restrict__ out, float* __restrict__ part1,
        int kTiles, int nwg) {
    __shared__ __align__(16) ushort_t As[2][BM * BK];
    __shared__ __align__(16) ushort_t Bs[2][BN * BK];

    const int tid = threadIdx.x;

    // T1: bijective XCD swizzle (nwg divisible by 8)
    const int orig = blockIdx.x;
    const int wgid = (orig & 7) * (nwg >> 3) + (orig >> 3);
    const int split = wgid >> 9;            // 0 or 1
    const int bm = (wgid & 511) >> 3;       // 0..63
    const int bn = wgid & 7;                // 0..7
    const int mBase = bm * BM, nBase = bn * BN;
    const size_t kOff = (size_t)split * kTiles * BK;

    const int lane = tid & 63;
    const int w = tid >> 6;                 // 4 waves, 2x2 grid of 64x64 sub-tiles
    const int wr = (w >> 1) * 64, wc = (w & 1) * 64;
    const int fr = lane & 15;
    const int ks = (lane >> 4) * 8;         // k-slot elem offset (0/8/16/24)

    // staging: per round 256 threads x 16B = 64 rows of 64B; 2 rounds per matrix.
    // T2 swizzle: element col ^= (row&3)<<3 (both source and read sides).
    const int srow = tid >> 2;                                  // 0..63
    const int scolE = ((tid & 3) << 3) ^ ((srow & 3) << 3);     // pre-swizzled source col
    const int sdst = (tid & ~63) * 8;                           // wave-uniform elem offset

    auto stageA = [&](int kb, int buf, int it) {
        const ushort_t* g = Af + (size_t)(mBase + it * 64 + srow) * K_DIM
                               + kOff + (size_t)kb * BK + scolE;
        llds16(g, &As[buf][it * 2048 + sdst]);
    };
    auto stageB = [&](int kb, int buf, int it) {
        const ushort_t* g = Wf + (size_t)(nBase + it * 64 + srow) * K_DIM
                               + kOff + (size_t)kb * BK + scolE;
        llds16(g, &Bs[buf][it * 2048 + sdst]);
    };

    // read offsets (loop-invariant), swizzled to match staging
    int offA[4], offB[4];
    #pragma unroll
    for (int m = 0; m < 4; ++m) {
        int row = wr + m * 16 + fr;
        offA[m] = row * BK + (ks ^ ((row & 3) << 3));
    }
    #pragma unroll
    for (int n = 0; n < 4; ++n) {
        int row = wc + n * 16 + fr;
        offB[n] = row * BK + (ks ^ ((row & 3) << 3));
    }

    f32x4 acc[4][4];
    #pragma unroll
    for (int m = 0; m < 4; ++m)
        #pragma unroll
        for (int n = 0; n < 4; ++n) acc[m][n] = (f32x4){0.f, 0.f, 0.f, 0.f};

    stageA(0, 0, 0); stageA(0, 0, 1);
    stageB(0, 0, 0); stageB(0, 0, 1);
    __syncthreads();   // drains vmcnt(0)

    for (int kb = 0; kb < kTiles; ++kb) {
        const int cur = kb & 1;
        if (kb + 1 < kTiles) {
            stageA(kb + 1, cur ^ 1, 0); stageA(kb + 1, cur ^ 1, 1);
            stageB(kb + 1, cur ^ 1, 0); stageB(kb + 1, cur ^ 1, 1);
        }

        const ushort_t* A_ = As[cur];
        const ushort_t* B_ = Bs[cur];
        short8 a[4], b[4];
        #pragma unroll
        for (int m = 0; m < 4; ++m) a[m] = *(const short8*)&A_[offA[m]];
        #pragma unroll
        for (int n = 0; n < 4; ++n) b[n] = *(const short8*)&B_[offB[n]];
        #pragma unroll
        for (int m = 0; m < 4; ++m)
            #pragma unroll
            for (int n = 0; n < 4; ++n)
                acc[m][n] = MFMA(a[m], b[n], acc[m][n]);

        __syncthreads();   // next-tile stage drained + everyone done reading cur
    }

    // epilogue: C/D layout col=lane&15, row=(lane>>4)*4+r
    float* obase = split ? part1 : out;
    const int orow = (lane >> 4) * 4;
    const int ocol = lane & 15;
    #pragma unroll
    for (int m = 0; m < 4; ++m)
        #pragma unroll
        for (int n = 0; n < 4; ++n) {
            size_t base = (size_t)(mBase + wr + m * 16 + orow) * O_DIM
                        + (nBase + wc + n * 16 + ocol);
            #pragma unroll
            for (int r = 0; r < 4; ++r)
                obase[base + (size_t)r * O_DIM] = acc[m][n][r];
        }
}

// ---------------- reduce: out += part1 (float4) ----------------
__global__ __launch_bounds__(256) void reduce_kernel(
        float* __restrict__ out, const float* __restrict__ p1) {
    int i = blockIdx.x * 256 + threadIdx.x;   // float4 index, 2M total
    f32x4 a = ((const f32x4*)out)[i];
    f32x4 b = ((const f32x4*)p1)[i];
    ((f32x4*)out)[i] = a + b;
}

extern "C" void kernel_launch(void* const* d_in, const int* in_sizes, int n_in,
                              void* d_out, int out_size, void* d_ws, size_t ws_size,
                              hipStream_t stream) {
    const float* x  = (const float*)d_in[0];
    const float* bw = (const float*)d_in[1];
    const float* sw = (const float*)d_in[2];
    float* out = (float*)d_out;

    // ws layout: Wf [1024 x 9216] bf16 (18.9 MB), Af [8192 x 9216] bf16 (151 MB),
    // part1 [8192 x 1024] fp32 (33.6 MB)
    const size_t nW = (size_t)O_DIM * K_DIM;
    const size_t nA = (size_t)B_DIM * K_DIM;
    ushort_t* Wf = (ushort_t*)d_ws;
    ushort_t* Af = Wf + nW;
    float* part1 = (float*)(Af + nA);
    const size_t need = (nW + nA) * 2 + (size_t)B_DIM * O_DIM * 4;

    const int nsplit = (ws_size >= need) ? 2 : 1;   // ws_size constant -> deterministic
    const int kTiles = (K_DIM / BK) / nsplit;       // 144 or 288
    const int nwg = 512 * nsplit;

    expand_w_kernel<<<(O_DIM * I_DIM / 2) / 256, 256, 0, stream>>>(bw, sw, Wf);
    expand_a_kernel<<<(B_DIM * I_DIM / 2) / 256, 256, 0, stream>>>(x, Af);
    gemm_bt<<<nwg, 256, 0, stream>>>(Af, Wf, out, part1, kTiles, nwg);
    if (nsplit == 2)
        reduce_kernel<<<(B_DIM * O_DIM / 4) / 256, 256, 0, stream>>>(out, part1);
}

// Round 4
// 171.506 us; speedup vs baseline: 2.1452x; 1.3694x over previous
//
#include <hip/hip_runtime.h>
#include <hip/hip_bf16.h>

// KAN layer as augmented GEMM:
//   Af[b, c*1024+i] = c==0 ? silu(x[b,i]) : basis_{c-1}(x[b,i])   (bf16)
//   Wf[o, c*1024+i] = c==0 ? base_w[o,i]  : spline_w[o,i,c-1]     (bf16)
//   out = Af @ Wf^T  (fp32 accum via MFMA)
//
// GEMM: 256x128 tile, BK=64, 8 waves (4Mx2N -> 64x64/wave), 3-buffer LDS
// ring (144KB, 1 block/CU), prefetch distance 2, counted vmcnt(6),
// 2 phases x 16 MFMA per K-tile with raw s_barrier + lgkmcnt(0) only,
// (row&7) 16B-slot XOR swizzle (0-conflict config from round 2),
// T5 setprio, T1 bijective XCD swizzle. No split-K.
#define B_DIM 8192
#define I_DIM 1024
#define O_DIM 1024
#define K_DIM 9216   // 9 * 1024

#define BM 256
#define BN 128
#define BK 64
#define NKT (K_DIM / BK)   // 144

typedef unsigned short ushort_t;
typedef __attribute__((ext_vector_type(8))) short short8;
typedef __attribute__((ext_vector_type(4))) float f32x4;

#define MFMA(a, b, c) __builtin_amdgcn_mfma_f32_16x16x32_bf16((a), (b), (c), 0, 0, 0)

__device__ __forceinline__ ushort_t f2bf(float f) {
    unsigned u = __float_as_uint(f);
    unsigned r = 0x7fffu + ((u >> 16) & 1u);
    return (ushort_t)((u + r) >> 16);
}

__device__ __forceinline__ void llds16(const ushort_t* g, ushort_t* l) {
    __builtin_amdgcn_global_load_lds(
        (const __attribute__((address_space(1))) unsigned int*)g,
        (__attribute__((address_space(3))) unsigned int*)l,
        16, 0, 0);
}

// ---------------- expansion: weights ----------------
__global__ __launch_bounds__(256) void expand_w_kernel(
        const float* __restrict__ bw, const float* __restrict__ sw,
        ushort_t* __restrict__ Wf) {
    int idx = blockIdx.x * 256 + threadIdx.x;   // one thread: (o, 2 consecutive i)
    int o = idx >> 9;
    int i = (idx & 511) << 1;
    ushort_t* out = Wf + (size_t)o * K_DIM + i;
    const float* bp = bw + ((size_t)o << 10) + i;
    *(unsigned*)out = (unsigned)f2bf(bp[0]) | ((unsigned)f2bf(bp[1]) << 16);
    const float* sp = sw + (((size_t)o << 10) + i) * 8;   // 16 contiguous floats
    float v[16];
    #pragma unroll
    for (int n = 0; n < 16; ++n) v[n] = sp[n];
    #pragma unroll
    for (int n = 0; n < 8; ++n)
        *(unsigned*)(out + (size_t)(n + 1) * 1024) =
            (unsigned)f2bf(v[n]) | ((unsigned)f2bf(v[8 + n]) << 16);
}

// ---------------- expansion: activations ----------------
__global__ __launch_bounds__(256) void expand_a_kernel(
        const float* __restrict__ x, ushort_t* __restrict__ Af) {
    int idx = blockIdx.x * 256 + threadIdx.x;   // one thread: (b, 2 consecutive i)
    int b = idx >> 9;
    int i = (idx & 511) << 1;
    const float* xp = x + ((size_t)b << 10) + i;
    float x0 = xp[0], x1 = xp[1];
    ushort_t* out = Af + (size_t)b * K_DIM + i;
    float s0 = x0 / (1.0f + __expf(-x0));
    float s1 = x1 / (1.0f + __expf(-x1));
    *(unsigned*)out = (unsigned)f2bf(s0) | ((unsigned)f2bf(s1) << 16);
    // quadratic B-spline basis, uniform knots -9..9 step 1.8
    float t0 = (x0 + 9.0f) * (1.0f / 1.8f);
    float t1 = (x1 + 9.0f) * (1.0f / 1.8f);
    float fj0 = floorf(t0), fj1 = floorf(t1);
    int j0 = (int)fj0, j1 = (int)fj1;
    float u0 = t0 - fj0, u1 = t1 - fj1;
    float p0 = 0.5f * (1.f - u0) * (1.f - u0);
    float p1 = 0.5f * (-2.f * u0 * u0 + 2.f * u0 + 1.f);
    float p2 = 0.5f * u0 * u0;
    float q0 = 0.5f * (1.f - u1) * (1.f - u1);
    float q1 = 0.5f * (-2.f * u1 * u1 + 2.f * u1 + 1.f);
    float q2 = 0.5f * u1 * u1;
    #pragma unroll
    for (int n = 0; n < 8; ++n) {
        float v0 = (n == j0 - 2) ? p0 : (n == j0 - 1) ? p1 : (n == j0) ? p2 : 0.f;
        float v1 = (n == j1 - 2) ? q0 : (n == j1 - 1) ? q1 : (n == j1) ? q2 : 0.f;
        *(unsigned*)(out + (size_t)(n + 1) * 1024) =
            (unsigned)f2bf(v0) | ((unsigned)f2bf(v1) << 16);
    }
}

// ---------------- GEMM: out[M=8192, N=1024] = Af[M,K] * Wf[N,K]^T ----------------
__global__ __launch_bounds__(512, 1) void gemm_bt(
        const ushort_t* __restrict__ Af,
        const ushort_t* __restrict__ Wf,
        float* __restrict__ out) {
    // 3-buffer ring: A 3x32KB + B 3x16KB = 144KB
    __shared__ __align__(16) ushort_t As[3][BM * BK];
    __shared__ __align__(16) ushort_t Bs[3][BN * BK];

    const int tid = threadIdx.x;

    // T1: bijective XCD swizzle (nwg=256 divisible by 8)
    const int orig = blockIdx.x;
    const int wgid = (orig & 7) * 32 + (orig >> 3);
    const int bm = wgid >> 3;               // 0..31
    const int bn = wgid & 7;                // 0..7
    const int mBase = bm * BM, nBase = bn * BN;

    const int lane = tid & 63;
    const int w = tid >> 6;                 // 8 waves: 4M x 2N
    const int wr = (w >> 1) * 64, wc = (w & 1) * 64;
    const int fr = lane & 15;
    const int kg = lane >> 4;               // k-group 0..3

    // staging: 512 threads x 16B = 8KB per round = 64 rows of 128B.
    // T2 swizzle: 16B slot ^= (row&7); source pre-swizzled, LDS dest linear.
    const int srow = tid >> 3;                                  // 0..63
    const int scolE = (((tid & 7) ^ (srow & 7)) << 3);          // pre-swizzled source col
    const int sdst = (tid & ~63) * 8;                           // wave-uniform elem offset

    auto stageA = [&](int t, int buf, int rnd) {
        const ushort_t* g = Af + (size_t)(mBase + rnd * 64 + srow) * K_DIM
                               + (size_t)t * BK + scolE;
        llds16(g, &As[buf][rnd * 4096 + sdst]);
    };
    auto stageB = [&](int t, int buf, int rnd) {
        const ushort_t* g = Wf + (size_t)(nBase + rnd * 64 + srow) * K_DIM
                               + (size_t)t * BK + scolE;
        llds16(g, &Bs[buf][rnd * 4096 + sdst]);
    };

    // fragment read offsets (loop-invariant): row*64 + swizzled 16B slot
    int offA[4][2], offB[4][2];
    #pragma unroll
    for (int m = 0; m < 4; ++m) {
        int row = wr + m * 16 + fr;
        #pragma unroll
        for (int kk = 0; kk < 2; ++kk)
            offA[m][kk] = row * BK + (((kk * 4 + kg) ^ (row & 7)) << 3);
    }
    #pragma unroll
    for (int n = 0; n < 4; ++n) {
        int row = wc + n * 16 + fr;
        #pragma unroll
        for (int kk = 0; kk < 2; ++kk)
            offB[n][kk] = row * BK + (((kk * 4 + kg) ^ (row & 7)) << 3);
    }

    f32x4 acc[4][4];
    #pragma unroll
    for (int m = 0; m < 4; ++m)
        #pragma unroll
        for (int n = 0; n < 4; ++n) acc[m][n] = (f32x4){0.f, 0.f, 0.f, 0.f};

    // prologue: tile0 -> buf0, tile1 -> buf1 (6 loads each per thread)
    stageA(0, 0, 0); stageA(0, 0, 1); stageA(0, 0, 2); stageA(0, 0, 3);
    stageB(0, 0, 0); stageB(0, 0, 1);
    stageA(1, 1, 0); stageA(1, 1, 1); stageA(1, 1, 2); stageA(1, 1, 3);
    stageB(1, 1, 0); stageB(1, 1, 1);

    int cur = 0;
    for (int t = 0; t < NKT; ++t) {
        // tile t resident: newest 6 outstanding = tile t+1's loads
        if (t + 1 < NKT) asm volatile("s_waitcnt vmcnt(6)" ::: "memory");
        else             asm volatile("s_waitcnt vmcnt(0)" ::: "memory");
        __builtin_amdgcn_s_barrier();   // all waves past iter t-1 ds_reads

        const int pf = (cur >= 1) ? cur - 1 : 2;   // (cur+2)%3
        const bool dopf = (t + 2 < NKT);
        const ushort_t* A_ = As[cur];
        const ushort_t* B_ = Bs[cur];

        // ---- phase 1: n-half 0 ----
        short8 a[4][2], b[2][2];
        #pragma unroll
        for (int m = 0; m < 4; ++m) {
            a[m][0] = *(const short8*)&A_[offA[m][0]];
            a[m][1] = *(const short8*)&A_[offA[m][1]];
        }
        #pragma unroll
        for (int n = 0; n < 2; ++n) {
            b[n][0] = *(const short8*)&B_[offB[n][0]];
            b[n][1] = *(const short8*)&B_[offB[n][1]];
        }
        if (dopf) { stageA(t + 2, pf, 0); stageA(t + 2, pf, 1); stageA(t + 2, pf, 2); }
        asm volatile("s_waitcnt lgkmcnt(0)" ::: "memory");
        __builtin_amdgcn_sched_barrier(0);
        __builtin_amdgcn_s_setprio(1);
        #pragma unroll
        for (int m = 0; m < 4; ++m)
            #pragma unroll
            for (int n = 0; n < 2; ++n) {
                acc[m][n] = MFMA(a[m][0], b[n][0], acc[m][n]);
                acc[m][n] = MFMA(a[m][1], b[n][1], acc[m][n]);
            }
        __builtin_amdgcn_s_setprio(0);
        __builtin_amdgcn_s_barrier();

        // ---- phase 2: n-half 1 ----
        short8 b2[2][2];
        #pragma unroll
        for (int n = 0; n < 2; ++n) {
            b2[n][0] = *(const short8*)&B_[offB[2 + n][0]];
            b2[n][1] = *(const short8*)&B_[offB[2 + n][1]];
        }
        if (dopf) { stageA(t + 2, pf, 3); stageB(t + 2, pf, 0); stageB(t + 2, pf, 1); }
        asm volatile("s_waitcnt lgkmcnt(0)" ::: "memory");
        __builtin_amdgcn_sched_barrier(0);
        __builtin_amdgcn_s_setprio(1);
        #pragma unroll
        for (int m = 0; m < 4; ++m)
            #pragma unroll
            for (int n = 0; n < 2; ++n) {
                acc[m][2 + n] = MFMA(a[m][0], b2[n][0], acc[m][2 + n]);
                acc[m][2 + n] = MFMA(a[m][1], b2[n][1], acc[m][2 + n]);
            }
        __builtin_amdgcn_s_setprio(0);

        cur = (cur + 1 == 3) ? 0 : cur + 1;
    }

    // epilogue: C/D layout col=lane&15, row=(lane>>4)*4+r
    const int orow = (lane >> 4) * 4;
    const int ocol = lane & 15;
    #pragma unroll
    for (int m = 0; m < 4; ++m)
        #pragma unroll
        for (int n = 0; n < 4; ++n) {
            size_t base = (size_t)(mBase + wr + m * 16 + orow) * O_DIM
                        + (nBase + wc + n * 16 + ocol);
            #pragma unroll
            for (int r = 0; r < 4; ++r)
                out[base + (size_t)r * O_DIM] = acc[m][n][r];
        }
}

extern "C" void kernel_launch(void* const* d_in, const int* in_sizes, int n_in,
                              void* d_out, int out_size, void* d_ws, size_t ws_size,
                              hipStream_t stream) {
    const float* x  = (const float*)d_in[0];
    const float* bw = (const float*)d_in[1];
    const float* sw = (const float*)d_in[2];
    float* out = (float*)d_out;

    // ws layout: Wf [1024 x 9216] bf16 (18.9 MB) then Af [8192 x 9216] bf16 (151 MB)
    ushort_t* Wf = (ushort_t*)d_ws;
    ushort_t* Af = Wf + (size_t)O_DIM * K_DIM;

    expand_w_kernel<<<(O_DIM * I_DIM / 2) / 256, 256, 0, stream>>>(bw, sw, Wf);
    expand_a_kernel<<<(B_DIM * I_DIM / 2) / 256, 256, 0, stream>>>(x, Af);
    gemm_bt<<<(B_DIM / BM) * (O_DIM / BN), 512, 0, stream>>>(Af, Wf, out);
}